// Round 7
// baseline (489.439 us; speedup 1.0000x reference)
//
#include <hip/hip_runtime.h>
#include <stdint.h>

#define TPB 1024
#define BM 64
#define CTXD 256
#define HID 128
#define TSTEPS 48
#define DTC (1.0f/30.0f)

typedef short short8 __attribute__((ext_vector_type(8)));
typedef float f32x4 __attribute__((ext_vector_type(4)));
typedef float f32x2 __attribute__((ext_vector_type(2)));

// ---------------- LDS layout (bytes) ----------------
// all tiles stride 256B (or 512B ctx), XOR-swizzled byte ^= (row&15)<<4:
// 16 distinct 16B slots per row -> conflict-free b128 column reads.
#define OFF_WHH 0                 // W_hh bf16 [384][128]
#define OFF_W1  98304             // W1 bf16 [64][128]
#define OFF_H   114688            // loop: 2 x h bf16 [64][128] (16384 each); phase A: ctx [64][256] (32768)
#define HBUFSZ  16384
#define CSTRIDE 512
#define OFF_PART 147456           // delta partials f32 [4 mt][16 l15][4 jt][2] = 2048 B
#define LDS_BYTES 149504

__device__ __forceinline__ uint32_t cvtpk_bf16(float lo, float hi) {
    uint32_t r;
    asm("v_cvt_pk_bf16_f32 %0, %1, %2" : "=v"(r) : "v"(lo), "v"(hi));
    return r;
}
__device__ __forceinline__ uint32_t pkh2(float a, float b) {
    union { _Float16 h[2]; uint32_t u; } v;
    v.h[0] = (_Float16)a; v.h[1] = (_Float16)b; return v.u;
}
__device__ __forceinline__ float h2lo(uint32_t u) {
    union { uint32_t u; _Float16 h[2]; } v; v.u = u; return (float)v.h[0];
}
__device__ __forceinline__ float h2hi(uint32_t u) {
    union { uint32_t u; _Float16 h[2]; } v; v.u = u; return (float)v.h[1];
}
__device__ __forceinline__ float fsigm(float x) {
    return __builtin_amdgcn_rcpf(1.0f + __expf(-x));
}
__device__ __forceinline__ float ftanhf(float x) {
    return fmaf(-2.0f, __builtin_amdgcn_rcpf(1.0f + __expf(2.0f * x)), 1.0f);
}
__device__ __forceinline__ short8 ldA8(const float* src) {
    f32x2 v0 = *(const f32x2*)(src + 0);
    f32x2 v1 = *(const f32x2*)(src + 2);
    f32x2 v2 = *(const f32x2*)(src + 4);
    f32x2 v3 = *(const f32x2*)(src + 6);
    union { short8 s; uint32_t u[4]; } r;
    r.u[0] = cvtpk_bf16(v0.x, v0.y);
    r.u[1] = cvtpk_bf16(v1.x, v1.y);
    r.u[2] = cvtpk_bf16(v2.x, v2.y);
    r.u[3] = cvtpk_bf16(v3.x, v3.y);
    return r.s;
}

// Occupancy contract: R5 (1024,4) and R6 (1024,1) both produced a 64-VGPR
// allocation + ~1.1 GB/dispatch scratch spill — at TPB=1024 the launch_bounds
// 2nd arg does NOT control the register budget on this toolchain. Set the
// backend attribute directly: exactly 4 waves/EU -> 512/4 = 128 VGPR budget,
// the working-set size this kernel was designed for (R3/R4 fit it in 128).
__global__ __attribute__((amdgpu_waves_per_eu(4, 4))) __launch_bounds__(TPB)
void dd_kernel(const float* __restrict__ ctx, const float* __restrict__ lv,
               const float* __restrict__ Winit, const float* __restrict__ binit,
               const float* __restrict__ Wih, const float* __restrict__ bih,
               const float* __restrict__ Whh, const float* __restrict__ bhh,
               const float* __restrict__ W1, const float* __restrict__ b1,
               const float* __restrict__ W2, const float* __restrict__ b2,
               float* __restrict__ out)
{
    extern __shared__ char smem[];
    const int tid  = threadIdx.x;
    const int w    = tid >> 6;          // wave 0..15
    const int lane = tid & 63;
    const int g    = (lane >> 4) & 3;
    const int l15  = lane & 15;
    const int row0 = blockIdx.x * BM;
    const int wsub = w & 7;             // GRU unit-tile (16 units)
    const int mtb  = (w >> 3) * 2;      // GRU row-tile base: waves 0-7 -> mt{0,1}, 8-15 -> mt{2,3}
    const int jt   = w & 3;             // MLP hidden tile
    const int msel = (w >> 2) & 1;      // MLP row tile = mtb + msel  (covers all 16 (jt,mt) atoms)

    // ---------------- stage weights / ctx into LDS (bf16, (row&15)<<4 XOR swizzle) ----------------
    for (int p = tid; p < 384 * 64; p += TPB) {           // W_hh
        int u = p >> 6, kp = p & 63;
        f32x2 v = *(const f32x2*)(Whh + u * HID + 2 * kp);
        *(uint32_t*)(smem + OFF_WHH + u * 256 + ((4 * kp) ^ ((u & 15) << 4))) = cvtpk_bf16(v.x, v.y);
    }
    for (int p = tid; p < 64 * 64; p += TPB) {            // W1
        int u = p >> 6, kp = p & 63;
        f32x2 v = *(const f32x2*)(W1 + u * HID + 2 * kp);
        *(uint32_t*)(smem + OFF_W1 + u * 256 + ((4 * kp) ^ ((u & 15) << 4))) = cvtpk_bf16(v.x, v.y);
    }
    for (int p = tid; p < 64 * 128; p += TPB) {           // ctx
        int r = p >> 7, kp = p & 127;
        f32x2 v = *(const f32x2*)(ctx + (size_t)(row0 + r) * CTXD + 2 * kp);
        *(uint32_t*)(smem + OFF_H + r * CSTRIDE + ((4 * kp) ^ ((r & 15) << 4))) = cvtpk_bf16(v.x, v.y);
    }

    // ---------------- per-lane loop constants (units u = 16*wsub + 4g + r) ----------------
    const int ub = 16 * wsub + 4 * g;
    uint32_t wdrp[4], wdzp[4], wdnp[4];   // rank-2 delta weights, f16-packed (x,y)
    float bhnc[4], b1c[4], w2c0[4], w2c1[4];
#pragma unroll
    for (int r = 0; r < 4; ++r) {
        int u = ub + r;
        wdrp[r] = pkh2(Wih[(size_t)u * 258 + 0],         Wih[(size_t)u * 258 + 1]);
        wdzp[r] = pkh2(Wih[(size_t)(128 + u) * 258 + 0], Wih[(size_t)(128 + u) * 258 + 1]);
        wdnp[r] = pkh2(Wih[(size_t)(256 + u) * 258 + 0], Wih[(size_t)(256 + u) * 258 + 1]);
        bhnc[r] = bhh[256 + u];
        int um = 16 * jt + 4 * g + r;
        b1c[r]  = b1[um];
        w2c0[r] = W2[um];
        w2c1[r] = W2[64 + um];
    }
    const float b2c0 = b2[0], b2c1 = b2[1];
    float dx[2], dy[2], pos0[2], pos1[2];
#pragma unroll
    for (int m = 0; m < 2; ++m) {
        f32x2 v = *(const f32x2*)(lv + (size_t)(row0 + 16 * (mtb + m) + l15) * 2);
        dx[m] = v.x * DTC; dy[m] = v.y * DTC;
        pos0[m] = 0.f; pos1[m] = 0.f;
    }

    __syncthreads();

    // ---------------- Phase A: gi tile + h0 (wave: unit-tile wsub x 2 row-tiles) ----------------
    f32x4 zero4 = {0.f, 0.f, 0.f, 0.f};
    f32x4 accA[4][2];
#pragma unroll
    for (int jl = 0; jl < 4; ++jl) { accA[jl][0] = zero4; accA[jl][1] = zero4; }

    const int u16  = 16 * wsub + l15;
    const int cswz = (16 * g) ^ (l15 << 4);   // col^row swizzle base; per-kk col = cswz ^ 64kk
    for (int kk = 0; kk < 8; ++kk) {
        const int cx = cswz ^ (64 * kk);
        short8 bf0 = *(const short8*)(smem + OFF_H + (16 * mtb + l15) * CSTRIDE + cx);
        short8 bf1 = *(const short8*)(smem + OFF_H + (16 * mtb + 16 + l15) * CSTRIDE + cx);
        short8 afR = ldA8(Wih + (size_t)u16 * 258 + 2 + 32 * kk + 8 * g);
        short8 afZ = ldA8(Wih + (size_t)(128 + u16) * 258 + 2 + 32 * kk + 8 * g);
        short8 afN = ldA8(Wih + (size_t)(256 + u16) * 258 + 2 + 32 * kk + 8 * g);
        short8 afH = ldA8(Winit + (size_t)u16 * 256 + 32 * kk + 8 * g);
        accA[0][0] = __builtin_amdgcn_mfma_f32_16x16x32_bf16(afR, bf0, accA[0][0], 0, 0, 0);
        accA[0][1] = __builtin_amdgcn_mfma_f32_16x16x32_bf16(afR, bf1, accA[0][1], 0, 0, 0);
        accA[1][0] = __builtin_amdgcn_mfma_f32_16x16x32_bf16(afZ, bf0, accA[1][0], 0, 0, 0);
        accA[1][1] = __builtin_amdgcn_mfma_f32_16x16x32_bf16(afZ, bf1, accA[1][1], 0, 0, 0);
        accA[2][0] = __builtin_amdgcn_mfma_f32_16x16x32_bf16(afN, bf0, accA[2][0], 0, 0, 0);
        accA[2][1] = __builtin_amdgcn_mfma_f32_16x16x32_bf16(afN, bf1, accA[2][1], 0, 0, 0);
        accA[3][0] = __builtin_amdgcn_mfma_f32_16x16x32_bf16(afH, bf0, accA[3][0], 0, 0, 0);
        accA[3][1] = __builtin_amdgcn_mfma_f32_16x16x32_bf16(afH, bf1, accA[3][1], 0, 0, 0);
    }

    // biases (transient) + gi pack (f16) + h0
    uint32_t gipR[2][2], gipZ[2][2], gipN[2][2];
    float hm[2][4];
    {
        float tbr[4], tbz[4], tbn[4], thi[4];
#pragma unroll
        for (int r = 0; r < 4; ++r) {
            int u = ub + r;
            tbr[r] = bih[u] + bhh[u];
            tbz[r] = bih[128 + u] + bhh[128 + u];
            tbn[r] = bih[256 + u];
            thi[r] = binit[u];
        }
#pragma unroll
        for (int m = 0; m < 2; ++m) {
            gipR[m][0] = pkh2(accA[0][m][0] + tbr[0], accA[0][m][1] + tbr[1]);
            gipR[m][1] = pkh2(accA[0][m][2] + tbr[2], accA[0][m][3] + tbr[3]);
            gipZ[m][0] = pkh2(accA[1][m][0] + tbz[0], accA[1][m][1] + tbz[1]);
            gipZ[m][1] = pkh2(accA[1][m][2] + tbz[2], accA[1][m][3] + tbz[3]);
            gipN[m][0] = pkh2(accA[2][m][0] + tbn[0], accA[2][m][1] + tbn[1]);
            gipN[m][1] = pkh2(accA[2][m][2] + tbn[2], accA[2][m][3] + tbn[3]);
#pragma unroll
            for (int r = 0; r < 4; ++r)
                hm[m][r] = ftanhf(accA[3][m][r] + thi[r]);
        }
    }
    __syncthreads();              // ctx reads done; h region reusable

    const int hwcol = (32 * wsub + 8 * g) ^ (l15 << 4);
#pragma unroll
    for (int m = 0; m < 2; ++m) {  // h0 -> buf0
        uint2 pk;
        pk.x = cvtpk_bf16(hm[m][0], hm[m][1]);
        pk.y = cvtpk_bf16(hm[m][2], hm[m][3]);
        *(uint2*)(smem + OFF_H + (16 * (mtb + m) + l15) * 256 + hwcol) = pk;
    }
    __syncthreads();

    const int uRb = OFF_WHH + (16 * wsub + l15) * 256;
    const int uZb = OFF_WHH + (128 + 16 * wsub + l15) * 256;
    const int uNb = OFF_WHH + (256 + 16 * wsub + l15) * 256;
    const int uWb = OFF_W1 + (16 * jt + l15) * 256;
    const int hrow0 = (16 * mtb + l15) * 256;
    const int hrow1 = (16 * mtb + 16 + l15) * 256;

    // ---------------- recurrence: 49 iterations (t==TSTEPS = MLP-only tail) ----------------
    for (int t = 0; t <= TSTEPS; ++t) {
        const int rbuf = OFF_H + (t & 1) * HBUFSZ;         // h_t
        const int wbuf = OFF_H + ((t + 1) & 1) * HBUFSZ;   // h_{t+1}
        f32x4 aR[2], aZ[2], aN[2];
        f32x4 a1 = zero4;
        if (t < TSTEPS) {
            // C-init: gi (no delta — delta applied post-MFMA in gates)
#pragma unroll
            for (int m = 0; m < 2; ++m) {
                aR[m][0] = h2lo(gipR[m][0]); aR[m][1] = h2hi(gipR[m][0]);
                aR[m][2] = h2lo(gipR[m][1]); aR[m][3] = h2hi(gipR[m][1]);
                aZ[m][0] = h2lo(gipZ[m][0]); aZ[m][1] = h2hi(gipZ[m][0]);
                aZ[m][2] = h2lo(gipZ[m][1]); aZ[m][3] = h2hi(gipZ[m][1]);
#pragma unroll
                for (int r = 0; r < 4; ++r) aN[m][r] = bhnc[r];
            }
#pragma unroll
            for (int kk = 0; kk < 4; ++kk) {
                const int cx = cswz ^ (64 * kk);
                short8 bf0 = *(const short8*)(smem + rbuf + hrow0 + cx);
                short8 bf1 = *(const short8*)(smem + rbuf + hrow1 + cx);
                short8 wfk = *(const short8*)(smem + uWb + cx);
                short8 fR  = *(const short8*)(smem + uRb + cx);
                short8 fZ  = *(const short8*)(smem + uZb + cx);
                short8 fN  = *(const short8*)(smem + uNb + cx);
                aR[0] = __builtin_amdgcn_mfma_f32_16x16x32_bf16(fR, bf0, aR[0], 0, 0, 0);
                aR[1] = __builtin_amdgcn_mfma_f32_16x16x32_bf16(fR, bf1, aR[1], 0, 0, 0);
                aZ[0] = __builtin_amdgcn_mfma_f32_16x16x32_bf16(fZ, bf0, aZ[0], 0, 0, 0);
                aZ[1] = __builtin_amdgcn_mfma_f32_16x16x32_bf16(fZ, bf1, aZ[1], 0, 0, 0);
                aN[0] = __builtin_amdgcn_mfma_f32_16x16x32_bf16(fN, bf0, aN[0], 0, 0, 0);
                aN[1] = __builtin_amdgcn_mfma_f32_16x16x32_bf16(fN, bf1, aN[1], 0, 0, 0);
                short8 bfM = msel ? bf1 : bf0;
                a1 = __builtin_amdgcn_mfma_f32_16x16x32_bf16(wfk, bfM, a1, 0, 0, 0);
            }
        } else {                   // tail: MLP(h_48) only
#pragma unroll
            for (int kk = 0; kk < 4; ++kk) {
                const int cx = cswz ^ (64 * kk);
                short8 bfM = *(const short8*)(smem + rbuf + (msel ? hrow1 : hrow0) + cx);
                short8 wfk = *(const short8*)(smem + uWb + cx);
                a1 = __builtin_amdgcn_mfma_f32_16x16x32_bf16(wfk, bfM, a1, 0, 0, 0);
            }
        }
        // MLP epilogue -> partial (jt, mtb+msel)
        {
            float s0 = 0.f, s1 = 0.f;
#pragma unroll
            for (int r = 0; r < 4; ++r) {
                float hv = fmaxf(a1[r] + b1c[r], 0.f);
                s0 = fmaf(hv, w2c0[r], s0);
                s1 = fmaf(hv, w2c1[r], s1);
            }
            s0 += __shfl_xor(s0, 16, 64); s0 += __shfl_xor(s0, 32, 64);
            s1 += __shfl_xor(s1, 16, 64); s1 += __shfl_xor(s1, 32, 64);
            if (lane < 16) {
                f32x2 pw; pw.x = s0; pw.y = s1;
                *(f32x2*)(smem + OFF_PART + (mtb + msel) * 512 + l15 * 32 + jt * 8) = pw;
            }
        }
        __syncthreads();          // barrier B: partials visible
        if (t > 0) {
#pragma unroll
            for (int m = 0; m < 2; ++m) {
                f32x4 q0 = *(const f32x4*)(smem + OFF_PART + (mtb + m) * 512 + l15 * 32);
                f32x4 q1 = *(const f32x4*)(smem + OFF_PART + (mtb + m) * 512 + l15 * 32 + 16);
                float pdx = (q0[0] + q0[2]) + (q1[0] + q1[2]) + b2c0;
                float pdy = (q0[1] + q0[3]) + (q1[1] + q1[3]) + b2c1;
                dx[m] = pdx; dy[m] = pdy;
                pos0[m] += pdx; pos1[m] += pdy;
            }
            if ((w == 0 || w == 8) && lane < 16) {
#pragma unroll
                for (int m = 0; m < 2; ++m) {
                    f32x2 o2; o2.x = pos0[m]; o2.y = pos1[m];
                    *(f32x2*)(out + (size_t)(row0 + 16 * (mtb + m) + l15) * (TSTEPS * 2) + 2 * (t - 1)) = o2;
                }
            }
        }
        if (t < TSTEPS) {
            // unpack rank-2 weights once per step
            float wr0[4], wr1[4], wz0[4], wz1[4], wn0[4], wn1[4];
#pragma unroll
            for (int r = 0; r < 4; ++r) {
                wr0[r] = h2lo(wdrp[r]); wr1[r] = h2hi(wdrp[r]);
                wz0[r] = h2lo(wdzp[r]); wz1[r] = h2hi(wdzp[r]);
                wn0[r] = h2lo(wdnp[r]); wn1[r] = h2hi(wdnp[r]);
            }
#pragma unroll
            for (int m = 0; m < 2; ++m) {
                float gn[4];
                gn[0] = h2lo(gipN[m][0]); gn[1] = h2hi(gipN[m][0]);
                gn[2] = h2lo(gipN[m][1]); gn[3] = h2hi(gipN[m][1]);
#pragma unroll
                for (int r = 0; r < 4; ++r) {
                    float rr  = fsigm(fmaf(dy[m], wr1[r], fmaf(dx[m], wr0[r], aR[m][r])));
                    float zz  = fsigm(fmaf(dy[m], wz1[r], fmaf(dx[m], wz0[r], aZ[m][r])));
                    float inn = fmaf(dy[m], wn1[r], fmaf(dx[m], wn0[r], gn[r]));
                    float nn  = ftanhf(fmaf(rr, aN[m][r], inn));
                    hm[m][r]  = fmaf(zz, hm[m][r] - nn, nn);
                }
                uint2 pk;
                pk.x = cvtpk_bf16(hm[m][0], hm[m][1]);
                pk.y = cvtpk_bf16(hm[m][2], hm[m][3]);
                *(uint2*)(smem + wbuf + (16 * (mtb + m) + l15) * 256 + hwcol) = pk;
            }
        }
        __syncthreads();          // barrier A: h_{t+1} visible
    }
}

extern "C" void kernel_launch(void* const* d_in, const int* in_sizes, int n_in,
                              void* d_out, int out_size, void* d_ws, size_t ws_size,
                              hipStream_t stream) {
    (void)in_sizes; (void)n_in; (void)d_ws; (void)ws_size; (void)out_size;
    const float* ctx   = (const float*)d_in[0];
    const float* lv    = (const float*)d_in[1];
    const float* Winit = (const float*)d_in[2];
    const float* binit = (const float*)d_in[3];
    const float* Wih   = (const float*)d_in[4];
    const float* bih   = (const float*)d_in[5];
    const float* Whh   = (const float*)d_in[6];
    const float* bhh   = (const float*)d_in[7];
    const float* W1    = (const float*)d_in[8];
    const float* b1    = (const float*)d_in[9];
    const float* W2    = (const float*)d_in[10];
    const float* b2    = (const float*)d_in[11];
    float* out = (float*)d_out;

    hipFuncSetAttribute(reinterpret_cast<const void*>(dd_kernel),
                        hipFuncAttributeMaxDynamicSharedMemorySize, LDS_BYTES);
    dd_kernel<<<16384 / BM, TPB, LDS_BYTES, stream>>>(
        ctx, lv, Winit, binit, Wih, bih, Whh, bhh, W1, b1, W2, b2, out);
}

// Round 8
// 204.036 us; speedup vs baseline: 2.3988x; 2.3988x over previous
//
#include <hip/hip_runtime.h>
#include <stdint.h>

#define TPB 512
#define BM 32
#define CTXD 256
#define HID 128
#define TSTEPS 48
#define DTC (1.0f/30.0f)

typedef short short8 __attribute__((ext_vector_type(8)));
typedef float f32x4 __attribute__((ext_vector_type(4)));
typedef float f32x2 __attribute__((ext_vector_type(2)));

// ---------------- LDS layout (bytes), per block (2 blocks/CU) ----------------
// W_N / W1 / h tiles: stride 256B, XOR swizzle byte ^= (row&15)<<4 -> conflict-free b128.
#define OFF_WN   0                // W_hh N-gate bf16 [128][128] = 32768
#define OFF_W1   32768            // W1 bf16 [64][128] = 16384
#define OFF_H    49152            // loop: 2 x h bf16 [32][128] (8192 each); phase A: ctx bf16 [32][256] (16384)
#define HBUFSZ   8192
#define CSTRIDE  512
#define OFF_PART 65536            // delta partials f32 [2 mt][16 l15][4 jt][2] = 1024
#define OFF_TWDR 66560            // rank-2 delta weights, f16-packed, [128] u32 per gate
#define OFF_TWDZ 67072
#define OFF_TWDN 67584
#define OFF_TBHN 68096            // bhh_n f32 [128]
#define OFF_TB1  68608            // b1 f32 [64]
#define OFF_TW2  68864            // W2 f32 [128] (as stored: [2][64])
#define LDS_BYTES 69632           // 2 x 69632 = 139264 <= 160 KiB -> 2 blocks/CU

__device__ __forceinline__ uint32_t cvtpk_bf16(float lo, float hi) {
    uint32_t r;
    asm("v_cvt_pk_bf16_f32 %0, %1, %2" : "=v"(r) : "v"(lo), "v"(hi));
    return r;
}
__device__ __forceinline__ uint32_t pkh2(float a, float b) {
    union { _Float16 h[2]; uint32_t u; } v;
    v.h[0] = (_Float16)a; v.h[1] = (_Float16)b; return v.u;
}
__device__ __forceinline__ float h2lo(uint32_t u) {
    union { uint32_t u; _Float16 h[2]; } v; v.u = u; return (float)v.h[0];
}
__device__ __forceinline__ float h2hi(uint32_t u) {
    union { uint32_t u; _Float16 h[2]; } v; v.u = u; return (float)v.h[1];
}
__device__ __forceinline__ float fsigm(float x) {
    return __builtin_amdgcn_rcpf(1.0f + __expf(-x));
}
__device__ __forceinline__ float ftanhf(float x) {
    return fmaf(-2.0f, __builtin_amdgcn_rcpf(1.0f + __expf(2.0f * x)), 1.0f);
}
__device__ __forceinline__ short8 ldA8(const float* src) {
    f32x2 v0 = *(const f32x2*)(src + 0);
    f32x2 v1 = *(const f32x2*)(src + 2);
    f32x2 v2 = *(const f32x2*)(src + 4);
    f32x2 v3 = *(const f32x2*)(src + 6);
    union { short8 s; uint32_t u[4]; } r;
    r.u[0] = cvtpk_bf16(v0.x, v0.y);
    r.u[1] = cvtpk_bf16(v1.x, v1.y);
    r.u[2] = cvtpk_bf16(v2.x, v2.y);
    r.u[3] = cvtpk_bf16(v3.x, v3.y);
    return r.s;
}

// VGPR contract: TPB=1024 pins a 64-VGPR allocation on this toolchain no matter
// which occupancy attribute is used (R5/R6/R7 all spilled ~1.1 GB/dispatch).
// (512,2) is the empirically proven 128-VGPR / zero-spill incantation (R3/R4).
// 16 waves/CU reached as 2 blocks x 8 waves; W_R/W_Z register-resident so the
// per-block LDS (68 KB) lets two blocks co-reside.
__global__ __launch_bounds__(TPB, 2)
void dd_kernel(const float* __restrict__ ctx, const float* __restrict__ lv,
               const float* __restrict__ Winit, const float* __restrict__ binit,
               const float* __restrict__ Wih, const float* __restrict__ bih,
               const float* __restrict__ Whh, const float* __restrict__ bhh,
               const float* __restrict__ W1, const float* __restrict__ b1,
               const float* __restrict__ W2, const float* __restrict__ b2,
               float* __restrict__ out)
{
    extern __shared__ char smem[];
    const int tid  = threadIdx.x;
    const int w    = tid >> 6;          // wave 0..7; owns GRU unit-tile 16w..16w+15, rows 0..31
    const int lane = tid & 63;
    const int g    = (lane >> 4) & 3;
    const int l15  = lane & 15;
    const int row0 = blockIdx.x * BM;
    const int jt   = w & 3;             // MLP hidden tile
    const int msel = (w >> 2) & 1;      // MLP row tile (8 waves = 4 jt x 2 mt)

    // ---------------- stage LDS: W_N, W1, ctx (swizzled) + constant tables ----------------
    for (int p = tid; p < 128 * 64; p += TPB) {           // W_hh N-gate rows 256..383
        int u = p >> 6, kp = p & 63;
        f32x2 v = *(const f32x2*)(Whh + (size_t)(256 + u) * HID + 2 * kp);
        *(uint32_t*)(smem + OFF_WN + u * 256 + ((4 * kp) ^ ((u & 15) << 4))) = cvtpk_bf16(v.x, v.y);
    }
    for (int p = tid; p < 64 * 64; p += TPB) {            // W1
        int u = p >> 6, kp = p & 63;
        f32x2 v = *(const f32x2*)(W1 + u * HID + 2 * kp);
        *(uint32_t*)(smem + OFF_W1 + u * 256 + ((4 * kp) ^ ((u & 15) << 4))) = cvtpk_bf16(v.x, v.y);
    }
    for (int p = tid; p < 32 * 128; p += TPB) {           // ctx (phase A)
        int r = p >> 7, kp = p & 127;
        f32x2 v = *(const f32x2*)(ctx + (size_t)(row0 + r) * CTXD + 2 * kp);
        *(uint32_t*)(smem + OFF_H + r * CSTRIDE + ((4 * kp) ^ ((r & 15) << 4))) = cvtpk_bf16(v.x, v.y);
    }
    if (tid < 128) {                                      // per-unit constant tables
        int u = tid;
        *(uint32_t*)(smem + OFF_TWDR + u * 4) = pkh2(Wih[(size_t)u * 258], Wih[(size_t)u * 258 + 1]);
        *(uint32_t*)(smem + OFF_TWDZ + u * 4) = pkh2(Wih[(size_t)(128 + u) * 258], Wih[(size_t)(128 + u) * 258 + 1]);
        *(uint32_t*)(smem + OFF_TWDN + u * 4) = pkh2(Wih[(size_t)(256 + u) * 258], Wih[(size_t)(256 + u) * 258 + 1]);
        *(float*)(smem + OFF_TBHN + u * 4) = bhh[256 + u];
        *(float*)(smem + OFF_TW2 + u * 4) = W2[u];
    }
    if (tid < 64) *(float*)(smem + OFF_TB1 + tid * 4) = b1[tid];

    // ---------------- register-resident W_R / W_Z fragments (step-invariant) ----------------
    const int u16 = 16 * w + l15;
    short8 wfr[4], wfz[4];
#pragma unroll
    for (int kk = 0; kk < 4; ++kk) {
        wfr[kk] = ldA8(Whh + (size_t)u16 * HID + 32 * kk + 8 * g);
        wfz[kk] = ldA8(Whh + (size_t)(128 + u16) * HID + 32 * kk + 8 * g);
    }

    const float b2c0 = b2[0], b2c1 = b2[1];
    float dx[2], dy[2], pos0[2], pos1[2];
#pragma unroll
    for (int m = 0; m < 2; ++m) {
        f32x2 v = *(const f32x2*)(lv + (size_t)(row0 + 16 * m + l15) * 2);
        dx[m] = v.x * DTC; dy[m] = v.y * DTC;
        pos0[m] = 0.f; pos1[m] = 0.f;
    }

    __syncthreads();

    // ---------------- Phase A: gi tile + h0 ----------------
    f32x4 zero4 = {0.f, 0.f, 0.f, 0.f};
    f32x4 accA[4][2];
#pragma unroll
    for (int jl = 0; jl < 4; ++jl) { accA[jl][0] = zero4; accA[jl][1] = zero4; }

    const int cswz = (16 * g) ^ (l15 << 4);   // col^row swizzle base
    for (int kk = 0; kk < 8; ++kk) {
        const int cx = cswz ^ (64 * kk);
        short8 bf0 = *(const short8*)(smem + OFF_H + l15 * CSTRIDE + cx);
        short8 bf1 = *(const short8*)(smem + OFF_H + (16 + l15) * CSTRIDE + cx);
        short8 afR = ldA8(Wih + (size_t)u16 * 258 + 2 + 32 * kk + 8 * g);
        short8 afZ = ldA8(Wih + (size_t)(128 + u16) * 258 + 2 + 32 * kk + 8 * g);
        short8 afN = ldA8(Wih + (size_t)(256 + u16) * 258 + 2 + 32 * kk + 8 * g);
        short8 afH = ldA8(Winit + (size_t)u16 * 256 + 32 * kk + 8 * g);
        accA[0][0] = __builtin_amdgcn_mfma_f32_16x16x32_bf16(afR, bf0, accA[0][0], 0, 0, 0);
        accA[0][1] = __builtin_amdgcn_mfma_f32_16x16x32_bf16(afR, bf1, accA[0][1], 0, 0, 0);
        accA[1][0] = __builtin_amdgcn_mfma_f32_16x16x32_bf16(afZ, bf0, accA[1][0], 0, 0, 0);
        accA[1][1] = __builtin_amdgcn_mfma_f32_16x16x32_bf16(afZ, bf1, accA[1][1], 0, 0, 0);
        accA[2][0] = __builtin_amdgcn_mfma_f32_16x16x32_bf16(afN, bf0, accA[2][0], 0, 0, 0);
        accA[2][1] = __builtin_amdgcn_mfma_f32_16x16x32_bf16(afN, bf1, accA[2][1], 0, 0, 0);
        accA[3][0] = __builtin_amdgcn_mfma_f32_16x16x32_bf16(afH, bf0, accA[3][0], 0, 0, 0);
        accA[3][1] = __builtin_amdgcn_mfma_f32_16x16x32_bf16(afH, bf1, accA[3][1], 0, 0, 0);
    }

    // gi pack (f16) + h0 (biases transient, global scalar loads)
    uint32_t gipR[2][2], gipZ[2][2], gipN[2][2];
    float hm[2][4];
    {
        const int ub = 16 * w + 4 * g;
        float tbr[4], tbz[4], tbn[4], thi[4];
#pragma unroll
        for (int r = 0; r < 4; ++r) {
            int u = ub + r;
            tbr[r] = bih[u] + bhh[u];
            tbz[r] = bih[128 + u] + bhh[128 + u];
            tbn[r] = bih[256 + u];
            thi[r] = binit[u];
        }
#pragma unroll
        for (int m = 0; m < 2; ++m) {
            gipR[m][0] = pkh2(accA[0][m][0] + tbr[0], accA[0][m][1] + tbr[1]);
            gipR[m][1] = pkh2(accA[0][m][2] + tbr[2], accA[0][m][3] + tbr[3]);
            gipZ[m][0] = pkh2(accA[1][m][0] + tbz[0], accA[1][m][1] + tbz[1]);
            gipZ[m][1] = pkh2(accA[1][m][2] + tbz[2], accA[1][m][3] + tbz[3]);
            gipN[m][0] = pkh2(accA[2][m][0] + tbn[0], accA[2][m][1] + tbn[1]);
            gipN[m][1] = pkh2(accA[2][m][2] + tbn[2], accA[2][m][3] + tbn[3]);
#pragma unroll
            for (int r = 0; r < 4; ++r)
                hm[m][r] = ftanhf(accA[3][m][r] + thi[r]);
        }
    }
    __syncthreads();              // ctx reads done; h region reusable

    const int hwcol = (32 * w + 8 * g) ^ (l15 << 4);
#pragma unroll
    for (int m = 0; m < 2; ++m) {  // h0 -> buf0
        uint2 pk;
        pk.x = cvtpk_bf16(hm[m][0], hm[m][1]);
        pk.y = cvtpk_bf16(hm[m][2], hm[m][3]);
        *(uint2*)(smem + OFF_H + (16 * m + l15) * 256 + hwcol) = pk;
    }
    __syncthreads();

    const int uNb = OFF_WN + u16 * 256;          // N-gate W row (LDS rows 0..127 = units)
    const int uWb = OFF_W1 + (16 * jt + l15) * 256;
    const int hrow0 = l15 * 256;
    const int hrow1 = (16 + l15) * 256;
    const int ub4 = (16 * w + 4 * g) * 4;        // table byte offset (broadcast per 16-lane group)
    const int um4 = (16 * jt + 4 * g) * 4;

    // ---------------- recurrence: 49 iterations (t==TSTEPS = MLP-only tail) ----------------
    for (int t = 0; t <= TSTEPS; ++t) {
        const int rbuf = OFF_H + (t & 1) * HBUFSZ;         // h_t
        const int wbuf = OFF_H + ((t + 1) & 1) * HBUFSZ;   // h_{t+1}
        f32x4 aR[2], aZ[2], aN[2];
        f32x4 a1 = zero4;
        if (t < TSTEPS) {
            f32x4 bh = *(const f32x4*)(smem + OFF_TBHN + ub4);   // bhh_n (broadcast read)
#pragma unroll
            for (int m = 0; m < 2; ++m) {
                aR[m][0] = h2lo(gipR[m][0]); aR[m][1] = h2hi(gipR[m][0]);
                aR[m][2] = h2lo(gipR[m][1]); aR[m][3] = h2hi(gipR[m][1]);
                aZ[m][0] = h2lo(gipZ[m][0]); aZ[m][1] = h2hi(gipZ[m][0]);
                aZ[m][2] = h2lo(gipZ[m][1]); aZ[m][3] = h2hi(gipZ[m][1]);
                aN[m] = bh;
            }
#pragma unroll
            for (int kk = 0; kk < 4; ++kk) {
                const int cx = cswz ^ (64 * kk);
                short8 bf0 = *(const short8*)(smem + rbuf + hrow0 + cx);
                short8 bf1 = *(const short8*)(smem + rbuf + hrow1 + cx);
                short8 fN  = *(const short8*)(smem + uNb + cx);
                short8 wfk = *(const short8*)(smem + uWb + cx);
                aR[0] = __builtin_amdgcn_mfma_f32_16x16x32_bf16(wfr[kk], bf0, aR[0], 0, 0, 0);
                aR[1] = __builtin_amdgcn_mfma_f32_16x16x32_bf16(wfr[kk], bf1, aR[1], 0, 0, 0);
                aZ[0] = __builtin_amdgcn_mfma_f32_16x16x32_bf16(wfz[kk], bf0, aZ[0], 0, 0, 0);
                aZ[1] = __builtin_amdgcn_mfma_f32_16x16x32_bf16(wfz[kk], bf1, aZ[1], 0, 0, 0);
                aN[0] = __builtin_amdgcn_mfma_f32_16x16x32_bf16(fN, bf0, aN[0], 0, 0, 0);
                aN[1] = __builtin_amdgcn_mfma_f32_16x16x32_bf16(fN, bf1, aN[1], 0, 0, 0);
                short8 bfM = msel ? bf1 : bf0;
                a1 = __builtin_amdgcn_mfma_f32_16x16x32_bf16(wfk, bfM, a1, 0, 0, 0);
            }
        } else {                   // tail: MLP(h_48) only
#pragma unroll
            for (int kk = 0; kk < 4; ++kk) {
                const int cx = cswz ^ (64 * kk);
                short8 bfM = *(const short8*)(smem + rbuf + (msel ? hrow1 : hrow0) + cx);
                short8 wfk = *(const short8*)(smem + uWb + cx);
                a1 = __builtin_amdgcn_mfma_f32_16x16x32_bf16(wfk, bfM, a1, 0, 0, 0);
            }
        }
        // MLP epilogue (b1/W2 from LDS tables, broadcast reads)
        {
            f32x4 b1v = *(const f32x4*)(smem + OFF_TB1 + um4);
            f32x4 w2a = *(const f32x4*)(smem + OFF_TW2 + um4);
            f32x4 w2b = *(const f32x4*)(smem + OFF_TW2 + 256 + um4);
            float s0 = 0.f, s1 = 0.f;
#pragma unroll
            for (int r = 0; r < 4; ++r) {
                float hv = fmaxf(a1[r] + b1v[r], 0.f);
                s0 = fmaf(hv, w2a[r], s0);
                s1 = fmaf(hv, w2b[r], s1);
            }
            s0 += __shfl_xor(s0, 16, 64); s0 += __shfl_xor(s0, 32, 64);
            s1 += __shfl_xor(s1, 16, 64); s1 += __shfl_xor(s1, 32, 64);
            if (lane < 16) {
                f32x2 pw; pw.x = s0; pw.y = s1;
                *(f32x2*)(smem + OFF_PART + msel * 512 + l15 * 32 + jt * 8) = pw;
            }
        }
        __syncthreads();          // barrier B: partials visible
        if (t > 0) {
#pragma unroll
            for (int m = 0; m < 2; ++m) {
                f32x4 q0 = *(const f32x4*)(smem + OFF_PART + m * 512 + l15 * 32);
                f32x4 q1 = *(const f32x4*)(smem + OFF_PART + m * 512 + l15 * 32 + 16);
                float pdx = (q0[0] + q0[2]) + (q1[0] + q1[2]) + b2c0;
                float pdy = (q0[1] + q0[3]) + (q1[1] + q1[3]) + b2c1;
                dx[m] = pdx; dy[m] = pdy;
                pos0[m] += pdx; pos1[m] += pdy;
            }
            if (w == 0 && lane < 16) {
#pragma unroll
                for (int m = 0; m < 2; ++m) {
                    f32x2 o2; o2.x = pos0[m]; o2.y = pos1[m];
                    *(f32x2*)(out + (size_t)(row0 + 16 * m + l15) * (TSTEPS * 2) + 2 * (t - 1)) = o2;
                }
            }
        }
        if (t < TSTEPS) {
            // gates: rank-2 delta weights from LDS tables (broadcast b128 reads)
            uint4 twr = *(const uint4*)(smem + OFF_TWDR + ub4);
            uint4 twz = *(const uint4*)(smem + OFF_TWDZ + ub4);
            uint4 twn = *(const uint4*)(smem + OFF_TWDN + ub4);
            float wr0[4], wr1[4], wz0[4], wz1[4], wn0[4], wn1[4];
            wr0[0] = h2lo(twr.x); wr1[0] = h2hi(twr.x);
            wr0[1] = h2lo(twr.y); wr1[1] = h2hi(twr.y);
            wr0[2] = h2lo(twr.z); wr1[2] = h2hi(twr.z);
            wr0[3] = h2lo(twr.w); wr1[3] = h2hi(twr.w);
            wz0[0] = h2lo(twz.x); wz1[0] = h2hi(twz.x);
            wz0[1] = h2lo(twz.y); wz1[1] = h2hi(twz.y);
            wz0[2] = h2lo(twz.z); wz1[2] = h2hi(twz.z);
            wz0[3] = h2lo(twz.w); wz1[3] = h2hi(twz.w);
            wn0[0] = h2lo(twn.x); wn1[0] = h2hi(twn.x);
            wn0[1] = h2lo(twn.y); wn1[1] = h2hi(twn.y);
            wn0[2] = h2lo(twn.z); wn1[2] = h2hi(twn.z);
            wn0[3] = h2lo(twn.w); wn1[3] = h2hi(twn.w);
#pragma unroll
            for (int m = 0; m < 2; ++m) {
                float gn[4];
                gn[0] = h2lo(gipN[m][0]); gn[1] = h2hi(gipN[m][0]);
                gn[2] = h2lo(gipN[m][1]); gn[3] = h2hi(gipN[m][1]);
#pragma unroll
                for (int r = 0; r < 4; ++r) {
                    float rr  = fsigm(fmaf(dy[m], wr1[r], fmaf(dx[m], wr0[r], aR[m][r])));
                    float zz  = fsigm(fmaf(dy[m], wz1[r], fmaf(dx[m], wz0[r], aZ[m][r])));
                    float inn = fmaf(dy[m], wn1[r], fmaf(dx[m], wn0[r], gn[r]));
                    float nn  = ftanhf(fmaf(rr, aN[m][r], inn));
                    hm[m][r]  = fmaf(zz, hm[m][r] - nn, nn);
                }
                uint2 pk;
                pk.x = cvtpk_bf16(hm[m][0], hm[m][1]);
                pk.y = cvtpk_bf16(hm[m][2], hm[m][3]);
                *(uint2*)(smem + wbuf + (16 * m + l15) * 256 + hwcol) = pk;
            }
        }
        __syncthreads();          // barrier A: h_{t+1} visible
    }
}

extern "C" void kernel_launch(void* const* d_in, const int* in_sizes, int n_in,
                              void* d_out, int out_size, void* d_ws, size_t ws_size,
                              hipStream_t stream) {
    (void)in_sizes; (void)n_in; (void)d_ws; (void)ws_size; (void)out_size;
    const float* ctx   = (const float*)d_in[0];
    const float* lv    = (const float*)d_in[1];
    const float* Winit = (const float*)d_in[2];
    const float* binit = (const float*)d_in[3];
    const float* Wih   = (const float*)d_in[4];
    const float* bih   = (const float*)d_in[5];
    const float* Whh   = (const float*)d_in[6];
    const float* bhh   = (const float*)d_in[7];
    const float* W1    = (const float*)d_in[8];
    const float* b1    = (const float*)d_in[9];
    const float* W2    = (const float*)d_in[10];
    const float* b2    = (const float*)d_in[11];
    float* out = (float*)d_out;

    hipFuncSetAttribute(reinterpret_cast<const void*>(dd_kernel),
                        hipFuncAttributeMaxDynamicSharedMemorySize, LDS_BYTES);
    dd_kernel<<<16384 / BM, TPB, LDS_BYTES, stream>>>(
        ctx, lv, Winit, binit, Wih, bih, Whh, bhh, W1, b1, W2, b2, out);
}

// Round 9
// 203.630 us; speedup vs baseline: 2.4036x; 1.0020x over previous
//
#include <hip/hip_runtime.h>
#include <stdint.h>

#define TPB 512
#define BM 32
#define CTXD 256
#define HID 128
#define TSTEPS 48
#define DTC (1.0f/30.0f)

typedef short short8 __attribute__((ext_vector_type(8)));
typedef float f32x4 __attribute__((ext_vector_type(4)));
typedef float f32x2 __attribute__((ext_vector_type(2)));

// ---------------- LDS layout (bytes), per block ----------------
// 53,248 B/block: BELOW 64 KB (R8 theory: >64KB dynamic-LDS request pins
// 1 block/CU large-LDS mode; 69.6KB blocks refused to co-reside despite
// 2x69.6 <= 160KB). 2 x 53.2 = 106 KB -> 2 blocks/CU.
// W_N / h tiles: stride 256B, XOR swizzle byte ^= (row&15)<<4 (conflict-free b128).
#define OFF_WN   0                // W_hh N-gate bf16 [128][128] = 32768
#define OFF_H    32768            // loop: 2 x h bf16 [32][128] (8192 each); phase A: ctx bf16 [32][256] (16384)
#define HBUFSZ   8192
#define CSTRIDE  512
#define OFF_PART 49152            // delta partials f32 [2 mt][16 l15][4 jt][2] = 1024
#define OFF_TWDR 50176            // rank-2 delta weights, f16-packed, [128] u32 per gate
#define OFF_TWDZ 50688
#define OFF_TWDN 51200
#define OFF_TBHN 51712            // bhh_n f32 [128]
#define OFF_TB1  52224            // b1 f32 [64]
#define OFF_TW2  52480            // W2 f32 [2][64]
#define LDS_BYTES 53248

__device__ __forceinline__ uint32_t cvtpk_bf16(float lo, float hi) {
    uint32_t r;
    asm("v_cvt_pk_bf16_f32 %0, %1, %2" : "=v"(r) : "v"(lo), "v"(hi));
    return r;
}
__device__ __forceinline__ uint32_t pkh2(float a, float b) {
    union { _Float16 h[2]; uint32_t u; } v;
    v.h[0] = (_Float16)a; v.h[1] = (_Float16)b; return v.u;
}
__device__ __forceinline__ float h2lo(uint32_t u) {
    union { uint32_t u; _Float16 h[2]; } v; v.u = u; return (float)v.h[0];
}
__device__ __forceinline__ float h2hi(uint32_t u) {
    union { uint32_t u; _Float16 h[2]; } v; v.u = u; return (float)v.h[1];
}
__device__ __forceinline__ float fsigm(float x) {
    return __builtin_amdgcn_rcpf(1.0f + __expf(-x));
}
__device__ __forceinline__ float ftanhf(float x) {
    return fmaf(-2.0f, __builtin_amdgcn_rcpf(1.0f + __expf(2.0f * x)), 1.0f);
}
__device__ __forceinline__ short8 ldA8(const float* src) {
    f32x2 v0 = *(const f32x2*)(src + 0);
    f32x2 v1 = *(const f32x2*)(src + 2);
    f32x2 v2 = *(const f32x2*)(src + 4);
    f32x2 v3 = *(const f32x2*)(src + 6);
    union { short8 s; uint32_t u[4]; } r;
    r.u[0] = cvtpk_bf16(v0.x, v0.y);
    r.u[1] = cvtpk_bf16(v1.x, v1.y);
    r.u[2] = cvtpk_bf16(v2.x, v2.y);
    r.u[3] = cvtpk_bf16(v3.x, v3.y);
    return r.s;
}

// VGPR contract: (512,2) = proven 128-VGPR / zero-spill (R3/R4/R8).
__global__ __launch_bounds__(TPB, 2)
void dd_kernel(const float* __restrict__ ctx, const float* __restrict__ lv,
               const float* __restrict__ Winit, const float* __restrict__ binit,
               const float* __restrict__ Wih, const float* __restrict__ bih,
               const float* __restrict__ Whh, const float* __restrict__ bhh,
               const float* __restrict__ W1, const float* __restrict__ b1,
               const float* __restrict__ W2, const float* __restrict__ b2,
               float* __restrict__ out)
{
    extern __shared__ char smem[];
    const int tid  = threadIdx.x;
    const int w    = tid >> 6;          // wave 0..7; owns GRU unit-tile 16w..16w+15, rows 0..31
    const int lane = tid & 63;
    const int g    = (lane >> 4) & 3;
    const int l15  = lane & 15;
    const int row0 = blockIdx.x * BM;
    const int jt   = w & 3;             // MLP hidden tile
    const int msel = (w >> 2) & 1;      // MLP row tile (8 waves = 4 jt x 2 mt)

    // ---------------- stage LDS: W_N, ctx (swizzled) + constant tables ----------------
    for (int p = tid; p < 128 * 64; p += TPB) {           // W_hh N-gate rows 256..383
        int u = p >> 6, kp = p & 63;
        f32x2 v = *(const f32x2*)(Whh + (size_t)(256 + u) * HID + 2 * kp);
        *(uint32_t*)(smem + OFF_WN + u * 256 + ((4 * kp) ^ ((u & 15) << 4))) = cvtpk_bf16(v.x, v.y);
    }
    for (int p = tid; p < 32 * 128; p += TPB) {           // ctx (phase A)
        int r = p >> 7, kp = p & 127;
        f32x2 v = *(const f32x2*)(ctx + (size_t)(row0 + r) * CTXD + 2 * kp);
        *(uint32_t*)(smem + OFF_H + r * CSTRIDE + ((4 * kp) ^ ((r & 15) << 4))) = cvtpk_bf16(v.x, v.y);
    }
    if (tid < 128) {                                      // per-unit constant tables
        int u = tid;
        *(uint32_t*)(smem + OFF_TWDR + u * 4) = pkh2(Wih[(size_t)u * 258], Wih[(size_t)u * 258 + 1]);
        *(uint32_t*)(smem + OFF_TWDZ + u * 4) = pkh2(Wih[(size_t)(128 + u) * 258], Wih[(size_t)(128 + u) * 258 + 1]);
        *(uint32_t*)(smem + OFF_TWDN + u * 4) = pkh2(Wih[(size_t)(256 + u) * 258], Wih[(size_t)(256 + u) * 258 + 1]);
        *(float*)(smem + OFF_TBHN + u * 4) = bhh[256 + u];
        *(float*)(smem + OFF_TW2 + u * 4) = W2[u];
    }
    if (tid < 64) *(float*)(smem + OFF_TB1 + tid * 4) = b1[tid];

    // ---------------- register-resident W_R / W_Z / W1 fragments (step-invariant) ----------------
    const int u16 = 16 * w + l15;
    short8 wfr[4], wfz[4], wf1[4];
#pragma unroll
    for (int kk = 0; kk < 4; ++kk) {
        wfr[kk] = ldA8(Whh + (size_t)u16 * HID + 32 * kk + 8 * g);
        wfz[kk] = ldA8(Whh + (size_t)(128 + u16) * HID + 32 * kk + 8 * g);
        wf1[kk] = ldA8(W1 + (size_t)(16 * jt + l15) * HID + 32 * kk + 8 * g);
    }

    const float b2c0 = b2[0], b2c1 = b2[1];
    float dx[2], dy[2], pos0[2], pos1[2];
#pragma unroll
    for (int m = 0; m < 2; ++m) {
        f32x2 v = *(const f32x2*)(lv + (size_t)(row0 + 16 * m + l15) * 2);
        dx[m] = v.x * DTC; dy[m] = v.y * DTC;
        pos0[m] = 0.f; pos1[m] = 0.f;
    }

    __syncthreads();

    // ---------------- Phase A: gi tile + h0 ----------------
    f32x4 zero4 = {0.f, 0.f, 0.f, 0.f};
    f32x4 accA[4][2];
#pragma unroll
    for (int jl = 0; jl < 4; ++jl) { accA[jl][0] = zero4; accA[jl][1] = zero4; }

    const int cswz = (16 * g) ^ (l15 << 4);   // col^row swizzle base
    for (int kk = 0; kk < 8; ++kk) {
        const int cx = cswz ^ (64 * kk);
        short8 bf0 = *(const short8*)(smem + OFF_H + l15 * CSTRIDE + cx);
        short8 bf1 = *(const short8*)(smem + OFF_H + (16 + l15) * CSTRIDE + cx);
        short8 afR = ldA8(Wih + (size_t)u16 * 258 + 2 + 32 * kk + 8 * g);
        short8 afZ = ldA8(Wih + (size_t)(128 + u16) * 258 + 2 + 32 * kk + 8 * g);
        short8 afN = ldA8(Wih + (size_t)(256 + u16) * 258 + 2 + 32 * kk + 8 * g);
        short8 afH = ldA8(Winit + (size_t)u16 * 256 + 32 * kk + 8 * g);
        accA[0][0] = __builtin_amdgcn_mfma_f32_16x16x32_bf16(afR, bf0, accA[0][0], 0, 0, 0);
        accA[0][1] = __builtin_amdgcn_mfma_f32_16x16x32_bf16(afR, bf1, accA[0][1], 0, 0, 0);
        accA[1][0] = __builtin_amdgcn_mfma_f32_16x16x32_bf16(afZ, bf0, accA[1][0], 0, 0, 0);
        accA[1][1] = __builtin_amdgcn_mfma_f32_16x16x32_bf16(afZ, bf1, accA[1][1], 0, 0, 0);
        accA[2][0] = __builtin_amdgcn_mfma_f32_16x16x32_bf16(afN, bf0, accA[2][0], 0, 0, 0);
        accA[2][1] = __builtin_amdgcn_mfma_f32_16x16x32_bf16(afN, bf1, accA[2][1], 0, 0, 0);
        accA[3][0] = __builtin_amdgcn_mfma_f32_16x16x32_bf16(afH, bf0, accA[3][0], 0, 0, 0);
        accA[3][1] = __builtin_amdgcn_mfma_f32_16x16x32_bf16(afH, bf1, accA[3][1], 0, 0, 0);
    }

    // gi pack (f16) + h0 (biases transient, global scalar loads)
    uint32_t gipR[2][2], gipZ[2][2], gipN[2][2];
    float hm[2][4];
    {
        const int ub = 16 * w + 4 * g;
        float tbr[4], tbz[4], tbn[4], thi[4];
#pragma unroll
        for (int r = 0; r < 4; ++r) {
            int u = ub + r;
            tbr[r] = bih[u] + bhh[u];
            tbz[r] = bih[128 + u] + bhh[128 + u];
            tbn[r] = bih[256 + u];
            thi[r] = binit[u];
        }
#pragma unroll
        for (int m = 0; m < 2; ++m) {
            gipR[m][0] = pkh2(accA[0][m][0] + tbr[0], accA[0][m][1] + tbr[1]);
            gipR[m][1] = pkh2(accA[0][m][2] + tbr[2], accA[0][m][3] + tbr[3]);
            gipZ[m][0] = pkh2(accA[1][m][0] + tbz[0], accA[1][m][1] + tbz[1]);
            gipZ[m][1] = pkh2(accA[1][m][2] + tbz[2], accA[1][m][3] + tbz[3]);
            gipN[m][0] = pkh2(accA[2][m][0] + tbn[0], accA[2][m][1] + tbn[1]);
            gipN[m][1] = pkh2(accA[2][m][2] + tbn[2], accA[2][m][3] + tbn[3]);
#pragma unroll
            for (int r = 0; r < 4; ++r)
                hm[m][r] = ftanhf(accA[3][m][r] + thi[r]);
        }
    }
    __syncthreads();              // ctx reads done; h region reusable

    const int hwcol = (32 * w + 8 * g) ^ (l15 << 4);
#pragma unroll
    for (int m = 0; m < 2; ++m) {  // h0 -> buf0
        uint2 pk;
        pk.x = cvtpk_bf16(hm[m][0], hm[m][1]);
        pk.y = cvtpk_bf16(hm[m][2], hm[m][3]);
        *(uint2*)(smem + OFF_H + (16 * m + l15) * 256 + hwcol) = pk;
    }
    __syncthreads();

    const int uNb = OFF_WN + u16 * 256;          // N-gate W row (LDS rows 0..127 = units)
    const int hrow0 = l15 * 256;
    const int hrow1 = (16 + l15) * 256;
    const int ub4 = (16 * w + 4 * g) * 4;        // table byte offset (broadcast per 16-lane group)
    const int um4 = (16 * jt + 4 * g) * 4;

    // ---------------- recurrence: 49 iterations (t==TSTEPS = MLP-only tail) ----------------
    for (int t = 0; t <= TSTEPS; ++t) {
        const int rbuf = OFF_H + (t & 1) * HBUFSZ;         // h_t
        const int wbuf = OFF_H + ((t + 1) & 1) * HBUFSZ;   // h_{t+1}
        f32x4 aR[2], aZ[2], aN[2];
        f32x4 a1 = zero4;
        if (t < TSTEPS) {
            f32x4 bh = *(const f32x4*)(smem + OFF_TBHN + ub4);   // bhh_n (broadcast read)
#pragma unroll
            for (int m = 0; m < 2; ++m) {
                aR[m][0] = h2lo(gipR[m][0]); aR[m][1] = h2hi(gipR[m][0]);
                aR[m][2] = h2lo(gipR[m][1]); aR[m][3] = h2hi(gipR[m][1]);
                aZ[m][0] = h2lo(gipZ[m][0]); aZ[m][1] = h2hi(gipZ[m][0]);
                aZ[m][2] = h2lo(gipZ[m][1]); aZ[m][3] = h2hi(gipZ[m][1]);
                aN[m] = bh;
            }
#pragma unroll
            for (int kk = 0; kk < 4; ++kk) {
                const int cx = cswz ^ (64 * kk);
                short8 bf0 = *(const short8*)(smem + rbuf + hrow0 + cx);
                short8 bf1 = *(const short8*)(smem + rbuf + hrow1 + cx);
                short8 fN  = *(const short8*)(smem + uNb + cx);
                aR[0] = __builtin_amdgcn_mfma_f32_16x16x32_bf16(wfr[kk], bf0, aR[0], 0, 0, 0);
                aR[1] = __builtin_amdgcn_mfma_f32_16x16x32_bf16(wfr[kk], bf1, aR[1], 0, 0, 0);
                aZ[0] = __builtin_amdgcn_mfma_f32_16x16x32_bf16(wfz[kk], bf0, aZ[0], 0, 0, 0);
                aZ[1] = __builtin_amdgcn_mfma_f32_16x16x32_bf16(wfz[kk], bf1, aZ[1], 0, 0, 0);
                aN[0] = __builtin_amdgcn_mfma_f32_16x16x32_bf16(fN, bf0, aN[0], 0, 0, 0);
                aN[1] = __builtin_amdgcn_mfma_f32_16x16x32_bf16(fN, bf1, aN[1], 0, 0, 0);
                short8 bfM = msel ? bf1 : bf0;
                a1 = __builtin_amdgcn_mfma_f32_16x16x32_bf16(wf1[kk], bfM, a1, 0, 0, 0);
            }
        } else {                   // tail: MLP(h_48) only
#pragma unroll
            for (int kk = 0; kk < 4; ++kk) {
                const int cx = cswz ^ (64 * kk);
                short8 bfM = *(const short8*)(smem + rbuf + (msel ? hrow1 : hrow0) + cx);
                a1 = __builtin_amdgcn_mfma_f32_16x16x32_bf16(wf1[kk], bfM, a1, 0, 0, 0);
            }
        }
        // MLP epilogue (b1/W2 from LDS tables, broadcast reads)
        {
            f32x4 b1v = *(const f32x4*)(smem + OFF_TB1 + um4);
            f32x4 w2a = *(const f32x4*)(smem + OFF_TW2 + um4);
            f32x4 w2b = *(const f32x4*)(smem + OFF_TW2 + 256 + um4);
            float s0 = 0.f, s1 = 0.f;
#pragma unroll
            for (int r = 0; r < 4; ++r) {
                float hv = fmaxf(a1[r] + b1v[r], 0.f);
                s0 = fmaf(hv, w2a[r], s0);
                s1 = fmaf(hv, w2b[r], s1);
            }
            s0 += __shfl_xor(s0, 16, 64); s0 += __shfl_xor(s0, 32, 64);
            s1 += __shfl_xor(s1, 16, 64); s1 += __shfl_xor(s1, 32, 64);
            if (lane < 16) {
                f32x2 pw; pw.x = s0; pw.y = s1;
                *(f32x2*)(smem + OFF_PART + msel * 512 + l15 * 32 + jt * 8) = pw;
            }
        }
        __syncthreads();          // barrier B: partials visible
        if (t > 0) {
#pragma unroll
            for (int m = 0; m < 2; ++m) {
                f32x4 q0 = *(const f32x4*)(smem + OFF_PART + m * 512 + l15 * 32);
                f32x4 q1 = *(const f32x4*)(smem + OFF_PART + m * 512 + l15 * 32 + 16);
                float pdx = (q0[0] + q0[2]) + (q1[0] + q1[2]) + b2c0;
                float pdy = (q0[1] + q0[3]) + (q1[1] + q1[3]) + b2c1;
                dx[m] = pdx; dy[m] = pdy;
                pos0[m] += pdx; pos1[m] += pdy;
            }
            if (w == 0 && lane < 16) {
#pragma unroll
                for (int m = 0; m < 2; ++m) {
                    f32x2 o2; o2.x = pos0[m]; o2.y = pos1[m];
                    *(f32x2*)(out + (size_t)(row0 + 16 * m + l15) * (TSTEPS * 2) + 2 * (t - 1)) = o2;
                }
            }
        }
        if (t < TSTEPS) {
            // gates: rank-2 delta weights from LDS tables (broadcast b128 reads)
            uint4 twr = *(const uint4*)(smem + OFF_TWDR + ub4);
            uint4 twz = *(const uint4*)(smem + OFF_TWDZ + ub4);
            uint4 twn = *(const uint4*)(smem + OFF_TWDN + ub4);
            float wr0[4], wr1[4], wz0[4], wz1[4], wn0[4], wn1[4];
            wr0[0] = h2lo(twr.x); wr1[0] = h2hi(twr.x);
            wr0[1] = h2lo(twr.y); wr1[1] = h2hi(twr.y);
            wr0[2] = h2lo(twr.z); wr1[2] = h2hi(twr.z);
            wr0[3] = h2lo(twr.w); wr1[3] = h2hi(twr.w);
            wz0[0] = h2lo(twz.x); wz1[0] = h2hi(twz.x);
            wz0[1] = h2lo(twz.y); wz1[1] = h2hi(twz.y);
            wz0[2] = h2lo(twz.z); wz1[2] = h2hi(twz.z);
            wz0[3] = h2lo(twz.w); wz1[3] = h2hi(twz.w);
            wn0[0] = h2lo(twn.x); wn1[0] = h2hi(twn.x);
            wn0[1] = h2lo(twn.y); wn1[1] = h2hi(twn.y);
            wn0[2] = h2lo(twn.z); wn1[2] = h2hi(twn.z);
            wn0[3] = h2lo(twn.w); wn1[3] = h2hi(twn.w);
#pragma unroll
            for (int m = 0; m < 2; ++m) {
                float gn[4];
                gn[0] = h2lo(gipN[m][0]); gn[1] = h2hi(gipN[m][0]);
                gn[2] = h2lo(gipN[m][1]); gn[3] = h2hi(gipN[m][1]);
#pragma unroll
                for (int r = 0; r < 4; ++r) {
                    float rr  = fsigm(fmaf(dy[m], wr1[r], fmaf(dx[m], wr0[r], aR[m][r])));
                    float zz  = fsigm(fmaf(dy[m], wz1[r], fmaf(dx[m], wz0[r], aZ[m][r])));
                    float inn = fmaf(dy[m], wn1[r], fmaf(dx[m], wn0[r], gn[r]));
                    float nn  = ftanhf(fmaf(rr, aN[m][r], inn));
                    hm[m][r]  = fmaf(zz, hm[m][r] - nn, nn);
                }
                uint2 pk;
                pk.x = cvtpk_bf16(hm[m][0], hm[m][1]);
                pk.y = cvtpk_bf16(hm[m][2], hm[m][3]);
                *(uint2*)(smem + wbuf + (16 * m + l15) * 256 + hwcol) = pk;
            }
        }
        __syncthreads();          // barrier A: h_{t+1} visible
    }
}

extern "C" void kernel_launch(void* const* d_in, const int* in_sizes, int n_in,
                              void* d_out, int out_size, void* d_ws, size_t ws_size,
                              hipStream_t stream) {
    (void)in_sizes; (void)n_in; (void)d_ws; (void)ws_size; (void)out_size;
    const float* ctx   = (const float*)d_in[0];
    const float* lv    = (const float*)d_in[1];
    const float* Winit = (const float*)d_in[2];
    const float* binit = (const float*)d_in[3];
    const float* Wih   = (const float*)d_in[4];
    const float* bih   = (const float*)d_in[5];
    const float* Whh   = (const float*)d_in[6];
    const float* bhh   = (const float*)d_in[7];
    const float* W1    = (const float*)d_in[8];
    const float* b1    = (const float*)d_in[9];
    const float* W2    = (const float*)d_in[10];
    const float* b2    = (const float*)d_in[11];
    float* out = (float*)d_out;

    hipFuncSetAttribute(reinterpret_cast<const void*>(dd_kernel),
                        hipFuncAttributeMaxDynamicSharedMemorySize, LDS_BYTES);
    dd_kernel<<<16384 / BM, TPB, LDS_BYTES, stream>>>(
        ctx, lv, Winit, binit, Wih, bih, Whh, bhh, W1, b1, W2, b2, out);
}